// Round 16
// baseline (536.731 us; speedup 1.0000x reference)
//
#include <hip/hip_runtime.h>
#include <hip/hip_bf16.h>
#include <math.h>

#define DEV __device__ __forceinline__

typedef short bf16x8 __attribute__((ext_vector_type(8)));
typedef short bf16x4 __attribute__((ext_vector_type(4)));
typedef float f32x4 __attribute__((ext_vector_type(4)));

static const int Nn = 2048;
static const int DIMd = 512;

DEV float bf2f(short u) {
    union { unsigned int i; float f; } c;
    c.i = ((unsigned int)(unsigned short)u) << 16;
    return c.f;
}

DEV short f2bf(float f) {
    union { float f; unsigned int i; } c;
    c.f = f;
    unsigned int u = c.i;
    unsigned int r = (u + 0x7fffu + ((u >> 16) & 1u)) >> 16;
    return (short)r;
}

// async global->LDS, 16B per lane (lane-linear LDS dest required)
DEV void gload16(const short* __restrict__ g, short* l) {
    __builtin_amdgcn_global_load_lds(
        (__attribute__((address_space(1))) void*)g,
        (__attribute__((address_space(3))) void*)l, 16, 0, 0);
}

// ---------------------------------------------------------------------------
// K0: transpose + cast f32 [K][N] -> bf16 [N][K]
// ---------------------------------------------------------------------------
__global__ void k_transpose_cast(const float* __restrict__ src,
                                 short* __restrict__ dst, int K, int N) {
    int o = blockIdx.x * 256 + threadIdx.x;
    if (o >= K * N) return;
    int n = o / K, k = o - n * K;
    dst[o] = f2bf(src[(size_t)k * N + n]);
}

// ---------------------------------------------------------------------------
// K1: row LayerNorm over DIM=512, f32 in -> bf16 out. One wave per row.
// ---------------------------------------------------------------------------
__global__ __launch_bounds__(256) void k_ln(const float* __restrict__ x,
                                            const float* __restrict__ g,
                                            const float* __restrict__ bta,
                                            short* __restrict__ xn) {
    int row = blockIdx.x * 4 + (threadIdx.x >> 6);
    int lane = threadIdx.x & 63;
    const float* xr = x + (size_t)row * DIMd;
    float4 v0 = ((const float4*)xr)[lane * 2];
    float4 v1 = ((const float4*)xr)[lane * 2 + 1];
    float f[8] = {v0.x, v0.y, v0.z, v0.w, v1.x, v1.y, v1.z, v1.w};
    float s = 0.f, sq = 0.f;
#pragma unroll
    for (int t = 0; t < 8; ++t) { s += f[t]; sq += f[t] * f[t]; }
#pragma unroll
    for (int off = 32; off >= 1; off >>= 1) {
        s += __shfl_xor(s, off);
        sq += __shfl_xor(sq, off);
    }
    float mu = s * (1.0f / 512.0f);
    float var = sq * (1.0f / 512.0f) - mu * mu;
    float rs = rsqrtf(var + 1e-5f);
    bf16x8 o;
#pragma unroll
    for (int t = 0; t < 8; ++t) {
        int c = lane * 8 + t;
        o[t] = f2bf((f[t] - mu) * rs * g[c] + bta[c]);
    }
    *(bf16x8*)(xn + (size_t)row * DIMd + lane * 8) = o;
}

// ---------------------------------------------------------------------------
// m97-style 128x128 tile GEMM main loop (A [M][K], B^T [N][K], k-contig).
// ---------------------------------------------------------------------------
DEV void gemm128_loop(const short* __restrict__ A, const short* __restrict__ B,
                      int K, int i0, int n0, int tid,
                      short* As, short* Bs, f32x4 acc[4][4]) {
    const int w = tid >> 6, wr = w >> 1, wc = w & 1;
    const int lane = tid & 63, fr = lane & 15, fq = lane >> 4;
    const int sr = tid >> 3, sc = (tid & 7) * 8;
    for (int k0 = 0; k0 < K; k0 += 64) {
#pragma unroll
        for (int L = 0; L < 4; ++L) {
            gload16(A + (size_t)(i0 + L * 32 + sr) * K + k0 + sc,
                    As + (L * 32 + sr) * 64 + sc);
            gload16(B + (size_t)(n0 + L * 32 + sr) * K + k0 + sc,
                    Bs + (L * 32 + sr) * 64 + sc);
        }
        __syncthreads();
#pragma unroll
        for (int kk = 0; kk < 2; ++kk) {
            bf16x8 af[4], bfr[4];
#pragma unroll
            for (int m = 0; m < 4; ++m)
                af[m] = *(const bf16x8*)(As + (wr * 64 + m * 16 + fr) * 64 + kk * 32 + fq * 8);
#pragma unroll
            for (int n = 0; n < 4; ++n)
                bfr[n] = *(const bf16x8*)(Bs + (wc * 64 + n * 16 + fr) * 64 + kk * 32 + fq * 8);
#pragma unroll
            for (int m = 0; m < 4; ++m)
#pragma unroll
                for (int n = 0; n < 4; ++n)
                    acc[m][n] = __builtin_amdgcn_mfma_f32_16x16x32_bf16(af[m], bfr[n], acc[m][n], 0, 0, 0);
        }
        __syncthreads();
    }
}

// ---------------------------------------------------------------------------
// K2: qkv = xn @ w_qkvT^T. Scatter epilogue into Q, K (k-contig) and Vt.
// Q is PRESCALED by 0.125 (exact pow-2) so scores come out of MFMA scaled.
// ---------------------------------------------------------------------------
__global__ __launch_bounds__(256) void k_qkv(const short* __restrict__ xn,
                                             const short* __restrict__ wT,
                                             short* __restrict__ Q,
                                             short* __restrict__ Kb,
                                             short* __restrict__ Vt) {
    __shared__ short As[128 * 64], Bs[128 * 64];
    int tid = threadIdx.x;
    int i0 = blockIdx.x * 128, n0 = blockIdx.y * 128;
    f32x4 acc[4][4] = {};
    gemm128_loop(xn, wT, DIMd, i0, n0, tid, As, Bs, acc);
    const int w = tid >> 6, wr = w >> 1, wc = w & 1;
    const int lane = tid & 63, fr = lane & 15, fq = lane >> 4;
#pragma unroll
    for (int m = 0; m < 4; ++m) {
#pragma unroll
        for (int n = 0; n < 4; ++n) {
#pragma unroll
            for (int r = 0; r < 4; ++r) {
                int row = i0 + wr * 64 + m * 16 + fq * 4 + r;
                int c = n0 + wc * 64 + n * 16 + fr;
                float v = acc[m][n][r];
                int b = row >> 11, i = row & 2047;
                int t = c >> 9, rem = c & 511;
                int h = rem >> 6, dd = rem & 63;
                size_t bh = (size_t)(b * 8 + h);
                if (t == 0)      Q [(bh * Nn + i) * 64 + dd] = f2bf(v * 0.125f);
                else if (t == 1) Kb[(bh * Nn + i) * 64 + dd] = f2bf(v);
                else             Vt[(bh * 64 + dd) * Nn + i] = f2bf(v);
            }
        }
    }
}

// ---------------------------------------------------------------------------
// K6: final = out_h @ w_outT^T + b_out. f32 out.
// ---------------------------------------------------------------------------
__global__ __launch_bounds__(256) void k_out(const short* __restrict__ outh,
                                             const short* __restrict__ wT,
                                             const float* __restrict__ bias,
                                             float* __restrict__ out) {
    __shared__ short As[128 * 64], Bs[128 * 64];
    int tid = threadIdx.x;
    int i0 = blockIdx.x * 128, n0 = blockIdx.y * 128;
    f32x4 acc[4][4] = {};
    gemm128_loop(outh, wT, 512, i0, n0, tid, As, Bs, acc);
    const int w = tid >> 6, wr = w >> 1, wc = w & 1;
    const int lane = tid & 63, fr = lane & 15, fq = lane >> 4;
#pragma unroll
    for (int m = 0; m < 4; ++m)
#pragma unroll
        for (int n = 0; n < 4; ++n)
#pragma unroll
            for (int r = 0; r < 4; ++r) {
                int row = i0 + wr * 64 + m * 16 + fq * 4 + r;
                int c = n0 + wc * 64 + n * 16 + fr;
                out[(size_t)row * 512 + c] = acc[m][n][r] + bias[c];
            }
}

// XCD-aware decode, 512-block grid: (b, i0 32-row, jh)  [k_stats]
DEV void decode_bid2(int bid, int& b, int& i0, int& jh) {
    int xcd = bid & 7, slot = bid >> 3;  // slot 0..63
    b = xcd >> 1;
    jh = xcd & 1;
    i0 = slot * 32;
}

// XCD-aware decode, 1024-block grid: (b, i0 16-row, jh)  [k_fused]
DEV void decode_bid3(int bid, int& b, int& i0, int& jh) {
    int xcd = bid & 7, slot = bid >> 3;  // slot 0..127
    b = xcd >> 1;
    jh = xcd & 1;
    i0 = slot * 16;
}

// ---------------------------------------------------------------------------
// K3a: stats partials. Block = (b, i0, jh); wave h owns head h, 32 q-rows,
// 1024 j (16 jt). Swapped QK^T on prescaled Q. Partial (m, l) per (bh, i).
// ---------------------------------------------------------------------------
__global__ __launch_bounds__(512)
__attribute__((amdgpu_waves_per_eu(4, 4)))
void k_stats(const short* __restrict__ Q,
             const short* __restrict__ Kb,
             float* __restrict__ mpart,
             float* __restrict__ lpart) {
    int b, i0, jh;
    decode_bid2(blockIdx.x, b, i0, jh);
    int tid = threadIdx.x, wv = tid >> 6, lane = tid & 63;
    int fr = lane & 15, fq = lane >> 4;
    size_t bh = (size_t)(b * 8 + wv);
    const short* qb = Q + (bh * Nn + i0) * 64;
    bf16x8 qf[2][2];
#pragma unroll
    for (int in = 0; in < 2; ++in)
#pragma unroll
        for (int kk = 0; kk < 2; ++kk)
            qf[in][kk] = *(const bf16x8*)(qb + (in * 16 + fr) * 64 + kk * 32 + fq * 8);
    float m[2] = {-1e30f, -1e30f}, l[2] = {0.f, 0.f};
    const short* kbase = Kb + bh * Nn * 64 + (size_t)jh * 1024 * 64;
    for (int jt = 0; jt < 16; ++jt) {
        const short* kb = kbase + jt * 64 * 64;
        f32x4 acc[4][2] = {};
#pragma unroll
        for (int kk = 0; kk < 2; ++kk)
#pragma unroll
            for (int jm = 0; jm < 4; ++jm) {
                bf16x8 kf = *(const bf16x8*)(kb + (jm * 16 + fr) * 64 + kk * 32 + fq * 8);
                acc[jm][0] = __builtin_amdgcn_mfma_f32_16x16x32_bf16(kf, qf[0][kk], acc[jm][0], 0, 0, 0);
                acc[jm][1] = __builtin_amdgcn_mfma_f32_16x16x32_bf16(kf, qf[1][kk], acc[jm][1], 0, 0, 0);
            }
#pragma unroll
        for (int in = 0; in < 2; ++in) {
            float mt = acc[0][in][0];
#pragma unroll
            for (int jm = 0; jm < 4; ++jm)
#pragma unroll
                for (int r = 0; r < 4; ++r) mt = fmaxf(mt, acc[jm][in][r]);
            mt = fmaxf(mt, __shfl_xor(mt, 16));
            mt = fmaxf(mt, __shfl_xor(mt, 32));
            float es = 0.f;
#pragma unroll
            for (int jm = 0; jm < 4; ++jm)
#pragma unroll
                for (int r = 0; r < 4; ++r)
                    es += __expf(acc[jm][in][r] - mt);
            es += __shfl_xor(es, 16);
            es += __shfl_xor(es, 32);
            float mn = fmaxf(m[in], mt);
            l[in] = l[in] * __expf(m[in] - mn) + es * __expf(mt - mn);
            m[in] = mn;
        }
    }
    if (fq == 0) {
#pragma unroll
        for (int in = 0; in < 2; ++in) {
            size_t o = (size_t)jh * 65536 + bh * Nn + i0 + in * 16 + fr;
            mpart[o] = m[in];
            lpart[o] = l[in];
        }
    }
}

// ---------------------------------------------------------------------------
// K3b: combine the two j-half stats -> zh = m + log(l). 65536 elems.
// ---------------------------------------------------------------------------
__global__ __launch_bounds__(256) void k_zcomb(const float* __restrict__ mpart,
                                               const float* __restrict__ lpart,
                                               float* __restrict__ zstat) {
    int idx = blockIdx.x * 256 + threadIdx.x;
    float m0 = mpart[idx], m1 = mpart[65536 + idx];
    float l0 = lpart[idx], l1 = lpart[65536 + idx];
    float M = fmaxf(m0, m1);
    float L = l0 * __expf(m0 - M) + l1 * __expf(m1 - M);
    zstat[idx] = M + __logf(L);
}

// ---------------------------------------------------------------------------
// K4 (round-16): r15's verified 16-row fused pass with waves_per_eu(4,4).
// r15 lesson: waves_per_eu(2,2) ITSELF capped the CU at 8 waves = 2 blocks,
// so the LDS shrink bought nothing (and 2x blocks = 2x barrier overhead ->
// 256 us). (4,4) allows 16 waves/CU = FOUR co-resident 4-wave blocks
// (LDS 4 x 34 KB = 136 <= 160 KB; min=4 needs <=40 KB/block, ok). VGPR cap
// at 4 waves/EU = 128 >= 116 natural pressure (r15 measured) -> no spill
// expected (the r9/r10 64-VGPR spill pathology was at 512 threads where
// natural pressure far exceeded the cap). 4 independent blocks' barriers
// interleave: one block's mix-VALU fills others' MFMA/load phases (m114).
// ---------------------------------------------------------------------------
__global__ __launch_bounds__(256)
__attribute__((amdgpu_waves_per_eu(4, 4)))
void k_fused(const short* __restrict__ Q, const short* __restrict__ Kb,
             const short* __restrict__ Vt, const float* __restrict__ zstat,
             const float* __restrict__ R, const float* __restrict__ rg,
             const float* __restrict__ rb, float* __restrict__ opart) {
    __shared__ short S_lds[8 * 16 * 64];  // [h][16i][64j] bf16, swz — 16 KB
    __shared__ short P_lds[8 * 16 * 64];  // [g][16i][64j] bf16, swz — 16 KB
    __shared__ float Rraw[64], Rc[64], rgs[8], rbs[8], zl[128];
    int b, i0, jh;
    decode_bid3(blockIdx.x, b, i0, jh);
    int tid = threadIdx.x, wv = tid >> 6, lane = tid & 63;
    int fr = lane & 15, fq = lane >> 4;
    if (tid < 64) Rraw[tid] = R[tid];
    if (tid < 8) { rgs[tid] = rg[tid]; rbs[tid] = rb[tid]; }
    if (tid < 128) zl[tid] = zstat[(size_t)(b * 8 + (tid >> 4)) * Nn + i0 + (tid & 15)];
    __syncthreads();
    if (tid < 64) {
        int h = tid >> 3;
        float mn = 0.f;
#pragma unroll
        for (int gg = 0; gg < 8; ++gg) mn += Rraw[h * 8 + gg];
        Rc[tid] = Rraw[tid] - mn * 0.125f;  // row-centered mix matrix
    }
    // per-wave heads: h0 = wv, h1 = wv + 4
    bf16x8 qf[2][2];  // [hp][kk]
    float zh[2];      // [hp]
#pragma unroll
    for (int hp = 0; hp < 2; ++hp) {
        int hh = wv + hp * 4;
        const short* qb = Q + ((size_t)(b * 8 + hh) * Nn + i0) * 64;
#pragma unroll
        for (int kk = 0; kk < 2; ++kk)
            qf[hp][kk] = *(const bf16x8*)(qb + fr * 64 + kk * 32 + fq * 8);
        zh[hp] = zl[hh * 16 + fr];
    }
    const short* kb0 = Kb + ((size_t)(b * 8 + wv) * Nn + jh * 1024) * 64;
    const short* kb1 = Kb + ((size_t)(b * 8 + wv + 4) * Nn + jh * 1024) * 64;
    const short* vb0 = Vt + (size_t)(b * 8 + wv) * 64 * Nn + jh * 1024;
    const short* vb1 = Vt + (size_t)(b * 8 + wv + 4) * 64 * Nn + jh * 1024;
    const int mi = tid >> 4, j4 = (tid & 15) * 4;  // mix ownership (16 rows)
    const int msw = (mi & 7) << 4;
    f32x4 acc_o[2][4] = {};  // [hp][dn]

    // phase A: QK^T (swapped, prescaled Q) + exp -> S, both heads
    auto phaseA = [&](int jt) {
#pragma unroll
        for (int hp = 0; hp < 2; ++hp) {
            const short* kb = (hp ? kb1 : kb0) + jt * 64 * 64;
            f32x4 acc[4] = {};
#pragma unroll
            for (int kk = 0; kk < 2; ++kk)
#pragma unroll
                for (int jm = 0; jm < 4; ++jm) {
                    bf16x8 kf = *(const bf16x8*)(kb + (jm * 16 + fr) * 64 + kk * 32 + fq * 8);
                    acc[jm] = __builtin_amdgcn_mfma_f32_16x16x32_bf16(kf, qf[hp][kk], acc[jm], 0, 0, 0);
                }
            char* Sh = (char*)S_lds + (wv + hp * 4) * 2048;
            int sw = (fr & 7) << 4;
#pragma unroll
            for (int jm = 0; jm < 4; ++jm) {
                bf16x4 pk;
#pragma unroll
                for (int r = 0; r < 4; ++r)
                    pk[r] = f2bf(__expf(acc[jm][r] - zh[hp]));
                int j0 = jm * 16 + fq * 4;
                *(bf16x4*)(Sh + fr * 128 + ((j0 * 2) ^ sw)) = pk;
            }
        }
    };
    // phase B: cross-head mix + head-LN, S -> P (one quad per thread)
    auto phaseB = [&]() {
        bf16x4 sh[8];
#pragma unroll
        for (int h = 0; h < 8; ++h)
            sh[h] = *(const bf16x4*)((char*)S_lds + h * 2048 + mi * 128 + ((j4 * 2) ^ msw));
        bf16x4 og[8];
#pragma unroll
        for (int e = 0; e < 4; ++e) {
            float pv[8];
#pragma unroll
            for (int h = 0; h < 8; ++h) pv[h] = bf2f(sh[h][e]);
            float cc[8];
#pragma unroll
            for (int gg = 0; gg < 8; ++gg) {
                float s = 0.f;
#pragma unroll
                for (int h = 0; h < 8; ++h) s += pv[h] * Rc[h * 8 + gg];
                cc[gg] = s;  // mean over gg is 0 by construction
            }
            float var = 0.f;
#pragma unroll
            for (int gg = 0; gg < 8; ++gg) var += cc[gg] * cc[gg];
            var *= 0.125f;
            float rs_ = rsqrtf(var + 1e-5f);
#pragma unroll
            for (int gg = 0; gg < 8; ++gg)
                og[gg][e] = f2bf(cc[gg] * rs_ * rgs[gg] + rbs[gg]);
        }
#pragma unroll
        for (int gg = 0; gg < 8; ++gg)
            *(bf16x4*)((char*)P_lds + gg * 2048 + mi * 128 + ((j4 * 2) ^ msw)) = og[gg];
    };
    // phase C: PV for both heads, P -> acc_o
    auto phaseC = [&](int jt) {
#pragma unroll
        for (int hp = 0; hp < 2; ++hp) {
            const short* vb = (hp ? vb1 : vb0) + jt * 64;
            char* Ph = (char*)P_lds + (wv + hp * 4) * 2048;
#pragma unroll
            for (int kk = 0; kk < 2; ++kk) {
                bf16x8 vf[4];
#pragma unroll
                for (int dn = 0; dn < 4; ++dn)
                    vf[dn] = *(const bf16x8*)(vb + (size_t)(dn * 16 + fr) * Nn + kk * 32 + fq * 8);
                bf16x8 pa = *(const bf16x8*)(Ph + fr * 128 +
                                             (((kk * 32 + fq * 8) * 2) ^ ((fr & 7) << 4)));
#pragma unroll
                for (int dn = 0; dn < 4; ++dn)
                    acc_o[hp][dn] = __builtin_amdgcn_mfma_f32_16x16x32_bf16(pa, vf[dn], acc_o[hp][dn], 0, 0, 0);
            }
        }
    };

    phaseA(0);
    for (int k = 0; k < 16; ++k) {
        __syncthreads();   // S(k) ready (first iter: Rc ready too)
        phaseB();
        __syncthreads();   // P(k) ready; B's S-reads done before A rewrites S
        phaseC(k);
        if (k < 15) phaseA(k + 1);
    }

    float* po = opart + (size_t)jh * 4194304 + ((size_t)b * Nn + i0) * 512;
#pragma unroll
    for (int hp = 0; hp < 2; ++hp)
#pragma unroll
        for (int dn = 0; dn < 4; ++dn)
#pragma unroll
            for (int r = 0; r < 4; ++r)
                po[(fq * 4 + r) * 512 + (wv + hp * 4) * 64 + dn * 16 + fr] =
                    acc_o[hp][dn][r];
}

// ---------------------------------------------------------------------------
// K5: sum the two j-half O partials -> outh bf16. 4,194,304 elements.
// ---------------------------------------------------------------------------
__global__ __launch_bounds__(256) void k_osum(const float* __restrict__ opart,
                                              short* __restrict__ outh) {
    int base = (blockIdx.x * 256 + threadIdx.x) * 4;
    f32x4 a = *(const f32x4*)(opart + base);
    f32x4 c = *(const f32x4*)(opart + 4194304 + base);
    bf16x4 o;
#pragma unroll
    for (int t = 0; t < 4; ++t) o[t] = f2bf(a[t] + c[t]);
    *(bf16x4*)(outh + base) = o;
}

extern "C" void kernel_launch(void* const* d_in, const int* in_sizes, int n_in,
                              void* d_out, int out_size, void* d_ws, size_t ws_size,
                              hipStream_t stream) {
    const float* x      = (const float*)d_in[0];
    const float* ln_g   = (const float*)d_in[1];
    const float* ln_b   = (const float*)d_in[2];
    const float* w_qkv  = (const float*)d_in[3];
    const float* reattn = (const float*)d_in[4];
    const float* rn_g   = (const float*)d_in[5];
    const float* rn_b   = (const float*)d_in[6];
    const float* w_out  = (const float*)d_in[7];
    const float* b_out  = (const float*)d_in[8];
    float* out = (float*)d_out;

    char* ws = (char*)d_ws;
    short* wqkvT = (short*)ws; ws += (size_t)1536 * 512 * 2;
    short* woutT = (short*)ws; ws += (size_t)512 * 512 * 2;
    short* xn    = (short*)ws; ws += (size_t)8192 * 512 * 2;   // dead after k_qkv
    short* Q     = (short*)ws; ws += (size_t)32 * 2048 * 64 * 2;
    short* Kb    = (short*)ws; ws += (size_t)32 * 2048 * 64 * 2;
    short* Vt    = (short*)ws; ws += (size_t)32 * 64 * 2048 * 2;
    short* outh  = (short*)ws; ws += (size_t)8192 * 512 * 2;
    float* opart = (float*)ws; ws += (size_t)2 * 4194304 * 4;  // 33.6 MB
    float* mpart = (float*)ws; ws += (size_t)2 * 65536 * 4;
    float* lpart = (float*)ws; ws += (size_t)2 * 65536 * 4;
    // zh stats alias the dead xn region (65536*4 = 256 KB << 8.39 MB)
    float* zstat = (float*)xn;

    k_transpose_cast<<<(512 * 1536 + 255) / 256, 256, 0, stream>>>(w_qkv, wqkvT, 512, 1536);
    k_transpose_cast<<<(512 * 512 + 255) / 256, 256, 0, stream>>>(w_out, woutT, 512, 512);
    k_ln<<<8192 / 4, 256, 0, stream>>>(x, ln_g, ln_b, xn);
    k_qkv<<<dim3(8192 / 128, 1536 / 128), 256, 0, stream>>>(xn, wqkvT, Q, Kb, Vt);

    k_stats<<<512, 512, 0, stream>>>(Q, Kb, mpart, lpart);
    k_zcomb<<<256, 256, 0, stream>>>(mpart, lpart, zstat);
    k_fused<<<1024, 256, 0, stream>>>(Q, Kb, Vt, zstat, reattn, rn_g, rn_b, opart);
    k_osum<<<4096, 256, 0, stream>>>(opart, outh);

    k_out<<<dim3(8192 / 128, 512 / 128), 256, 0, stream>>>(outh, woutT, b_out, out);
}

// Round 17
// 317.969 us; speedup vs baseline: 1.6880x; 1.6880x over previous
//
#include <hip/hip_runtime.h>
#include <hip/hip_bf16.h>
#include <math.h>

#define DEV __device__ __forceinline__

typedef short bf16x8 __attribute__((ext_vector_type(8)));
typedef short bf16x4 __attribute__((ext_vector_type(4)));
typedef float f32x4 __attribute__((ext_vector_type(4)));

static const int Nn = 2048;
static const int DIMd = 512;

DEV float bf2f(short u) {
    union { unsigned int i; float f; } c;
    c.i = ((unsigned int)(unsigned short)u) << 16;
    return c.f;
}

DEV short f2bf(float f) {
    union { float f; unsigned int i; } c;
    c.f = f;
    unsigned int u = c.i;
    unsigned int r = (u + 0x7fffu + ((u >> 16) & 1u)) >> 16;
    return (short)r;
}

// async global->LDS, 16B per lane (lane-linear LDS dest required)
DEV void gload16(const short* __restrict__ g, short* l) {
    __builtin_amdgcn_global_load_lds(
        (__attribute__((address_space(1))) void*)g,
        (__attribute__((address_space(3))) void*)l, 16, 0, 0);
}

// ---------------------------------------------------------------------------
// K0: transpose + cast f32 [K][N] -> bf16 [N][K]
// ---------------------------------------------------------------------------
__global__ void k_transpose_cast(const float* __restrict__ src,
                                 short* __restrict__ dst, int K, int N) {
    int o = blockIdx.x * 256 + threadIdx.x;
    if (o >= K * N) return;
    int n = o / K, k = o - n * K;
    dst[o] = f2bf(src[(size_t)k * N + n]);
}

// ---------------------------------------------------------------------------
// K1: row LayerNorm over DIM=512, f32 in -> bf16 out. One wave per row.
// ---------------------------------------------------------------------------
__global__ __launch_bounds__(256) void k_ln(const float* __restrict__ x,
                                            const float* __restrict__ g,
                                            const float* __restrict__ bta,
                                            short* __restrict__ xn) {
    int row = blockIdx.x * 4 + (threadIdx.x >> 6);
    int lane = threadIdx.x & 63;
    const float* xr = x + (size_t)row * DIMd;
    float4 v0 = ((const float4*)xr)[lane * 2];
    float4 v1 = ((const float4*)xr)[lane * 2 + 1];
    float f[8] = {v0.x, v0.y, v0.z, v0.w, v1.x, v1.y, v1.z, v1.w};
    float s = 0.f, sq = 0.f;
#pragma unroll
    for (int t = 0; t < 8; ++t) { s += f[t]; sq += f[t] * f[t]; }
#pragma unroll
    for (int off = 32; off >= 1; off >>= 1) {
        s += __shfl_xor(s, off);
        sq += __shfl_xor(sq, off);
    }
    float mu = s * (1.0f / 512.0f);
    float var = sq * (1.0f / 512.0f) - mu * mu;
    float rs = rsqrtf(var + 1e-5f);
    bf16x8 o;
#pragma unroll
    for (int t = 0; t < 8; ++t) {
        int c = lane * 8 + t;
        o[t] = f2bf((f[t] - mu) * rs * g[c] + bta[c]);
    }
    *(bf16x8*)(xn + (size_t)row * DIMd + lane * 8) = o;
}

// ---------------------------------------------------------------------------
// m97-style 128x128 tile GEMM main loop (A [M][K], B^T [N][K], k-contig).
// ---------------------------------------------------------------------------
DEV void gemm128_loop(const short* __restrict__ A, const short* __restrict__ B,
                      int K, int i0, int n0, int tid,
                      short* As, short* Bs, f32x4 acc[4][4]) {
    const int w = tid >> 6, wr = w >> 1, wc = w & 1;
    const int lane = tid & 63, fr = lane & 15, fq = lane >> 4;
    const int sr = tid >> 3, sc = (tid & 7) * 8;
    for (int k0 = 0; k0 < K; k0 += 64) {
#pragma unroll
        for (int L = 0; L < 4; ++L) {
            gload16(A + (size_t)(i0 + L * 32 + sr) * K + k0 + sc,
                    As + (L * 32 + sr) * 64 + sc);
            gload16(B + (size_t)(n0 + L * 32 + sr) * K + k0 + sc,
                    Bs + (L * 32 + sr) * 64 + sc);
        }
        __syncthreads();
#pragma unroll
        for (int kk = 0; kk < 2; ++kk) {
            bf16x8 af[4], bfr[4];
#pragma unroll
            for (int m = 0; m < 4; ++m)
                af[m] = *(const bf16x8*)(As + (wr * 64 + m * 16 + fr) * 64 + kk * 32 + fq * 8);
#pragma unroll
            for (int n = 0; n < 4; ++n)
                bfr[n] = *(const bf16x8*)(Bs + (wc * 64 + n * 16 + fr) * 64 + kk * 32 + fq * 8);
#pragma unroll
            for (int m = 0; m < 4; ++m)
#pragma unroll
                for (int n = 0; n < 4; ++n)
                    acc[m][n] = __builtin_amdgcn_mfma_f32_16x16x32_bf16(af[m], bfr[n], acc[m][n], 0, 0, 0);
        }
        __syncthreads();
    }
}

// ---------------------------------------------------------------------------
// K2: qkv = xn @ w_qkvT^T. Scatter epilogue into Q, K (k-contig) and Vt.
// Q is PRESCALED by 0.125 (exact pow-2) so scores come out of MFMA scaled.
// ---------------------------------------------------------------------------
__global__ __launch_bounds__(256) void k_qkv(const short* __restrict__ xn,
                                             const short* __restrict__ wT,
                                             short* __restrict__ Q,
                                             short* __restrict__ Kb,
                                             short* __restrict__ Vt) {
    __shared__ short As[128 * 64], Bs[128 * 64];
    int tid = threadIdx.x;
    int i0 = blockIdx.x * 128, n0 = blockIdx.y * 128;
    f32x4 acc[4][4] = {};
    gemm128_loop(xn, wT, DIMd, i0, n0, tid, As, Bs, acc);
    const int w = tid >> 6, wr = w >> 1, wc = w & 1;
    const int lane = tid & 63, fr = lane & 15, fq = lane >> 4;
#pragma unroll
    for (int m = 0; m < 4; ++m) {
#pragma unroll
        for (int n = 0; n < 4; ++n) {
#pragma unroll
            for (int r = 0; r < 4; ++r) {
                int row = i0 + wr * 64 + m * 16 + fq * 4 + r;
                int c = n0 + wc * 64 + n * 16 + fr;
                float v = acc[m][n][r];
                int b = row >> 11, i = row & 2047;
                int t = c >> 9, rem = c & 511;
                int h = rem >> 6, dd = rem & 63;
                size_t bh = (size_t)(b * 8 + h);
                if (t == 0)      Q [(bh * Nn + i) * 64 + dd] = f2bf(v * 0.125f);
                else if (t == 1) Kb[(bh * Nn + i) * 64 + dd] = f2bf(v);
                else             Vt[(bh * 64 + dd) * Nn + i] = f2bf(v);
            }
        }
    }
}

// ---------------------------------------------------------------------------
// K6: final = out_h @ w_outT^T + b_out. f32 out.
// ---------------------------------------------------------------------------
__global__ __launch_bounds__(256) void k_out(const short* __restrict__ outh,
                                             const short* __restrict__ wT,
                                             const float* __restrict__ bias,
                                             float* __restrict__ out) {
    __shared__ short As[128 * 64], Bs[128 * 64];
    int tid = threadIdx.x;
    int i0 = blockIdx.x * 128, n0 = blockIdx.y * 128;
    f32x4 acc[4][4] = {};
    gemm128_loop(outh, wT, 512, i0, n0, tid, As, Bs, acc);
    const int w = tid >> 6, wr = w >> 1, wc = w & 1;
    const int lane = tid & 63, fr = lane & 15, fq = lane >> 4;
#pragma unroll
    for (int m = 0; m < 4; ++m)
#pragma unroll
        for (int n = 0; n < 4; ++n)
#pragma unroll
            for (int r = 0; r < 4; ++r) {
                int row = i0 + wr * 64 + m * 16 + fq * 4 + r;
                int c = n0 + wc * 64 + n * 16 + fr;
                out[(size_t)row * 512 + c] = acc[m][n][r] + bias[c];
            }
}

// XCD-aware decode of a 512-block 1-D grid into (b, i0, jh). Blocks sharing
// (b, jh) land on one XCD => that XCD's L2 holds one K/V half-panel.
DEV void decode_bid2(int bid, int& b, int& i0, int& jh) {
    int xcd = bid & 7, slot = bid >> 3;  // slot 0..63
    b = xcd >> 1;
    jh = xcd & 1;
    i0 = slot * 32;
}

// ---------------------------------------------------------------------------
// K3a: stats partials. Block = (b, i0, jh); wave h owns head h, 32 q-rows,
// 1024 j (16 jt). Swapped QK^T on prescaled Q. Partial (m, l) per (bh, i).
// setprio(1) around the MFMA cluster (T5): lets MFMA-phase waves win issue
// over online-softmax VALU waves on the same CU.
// ---------------------------------------------------------------------------
__global__ __launch_bounds__(512)
__attribute__((amdgpu_waves_per_eu(4, 4)))
void k_stats(const short* __restrict__ Q,
             const short* __restrict__ Kb,
             float* __restrict__ mpart,
             float* __restrict__ lpart) {
    int b, i0, jh;
    decode_bid2(blockIdx.x, b, i0, jh);
    int tid = threadIdx.x, wv = tid >> 6, lane = tid & 63;
    int fr = lane & 15, fq = lane >> 4;
    size_t bh = (size_t)(b * 8 + wv);
    const short* qb = Q + (bh * Nn + i0) * 64;
    bf16x8 qf[2][2];
#pragma unroll
    for (int in = 0; in < 2; ++in)
#pragma unroll
        for (int kk = 0; kk < 2; ++kk)
            qf[in][kk] = *(const bf16x8*)(qb + (in * 16 + fr) * 64 + kk * 32 + fq * 8);
    float m[2] = {-1e30f, -1e30f}, l[2] = {0.f, 0.f};
    const short* kbase = Kb + bh * Nn * 64 + (size_t)jh * 1024 * 64;
    for (int jt = 0; jt < 16; ++jt) {
        const short* kb = kbase + jt * 64 * 64;
        f32x4 acc[4][2] = {};
        __builtin_amdgcn_s_setprio(1);
#pragma unroll
        for (int kk = 0; kk < 2; ++kk)
#pragma unroll
            for (int jm = 0; jm < 4; ++jm) {
                bf16x8 kf = *(const bf16x8*)(kb + (jm * 16 + fr) * 64 + kk * 32 + fq * 8);
                acc[jm][0] = __builtin_amdgcn_mfma_f32_16x16x32_bf16(kf, qf[0][kk], acc[jm][0], 0, 0, 0);
                acc[jm][1] = __builtin_amdgcn_mfma_f32_16x16x32_bf16(kf, qf[1][kk], acc[jm][1], 0, 0, 0);
            }
        __builtin_amdgcn_s_setprio(0);
#pragma unroll
        for (int in = 0; in < 2; ++in) {
            float mt = acc[0][in][0];
#pragma unroll
            for (int jm = 0; jm < 4; ++jm)
#pragma unroll
                for (int r = 0; r < 4; ++r) mt = fmaxf(mt, acc[jm][in][r]);
            mt = fmaxf(mt, __shfl_xor(mt, 16));
            mt = fmaxf(mt, __shfl_xor(mt, 32));
            float es = 0.f;
#pragma unroll
            for (int jm = 0; jm < 4; ++jm)
#pragma unroll
                for (int r = 0; r < 4; ++r)
                    es += __expf(acc[jm][in][r] - mt);
            es += __shfl_xor(es, 16);
            es += __shfl_xor(es, 32);
            float mn = fmaxf(m[in], mt);
            l[in] = l[in] * __expf(m[in] - mn) + es * __expf(mt - mn);
            m[in] = mn;
        }
    }
    if (fq == 0) {
#pragma unroll
        for (int in = 0; in < 2; ++in) {
            size_t o = (size_t)jh * 65536 + bh * Nn + i0 + in * 16 + fr;
            mpart[o] = m[in];
            lpart[o] = l[in];
        }
    }
}

// ---------------------------------------------------------------------------
// K3b: combine the two j-half stats -> zh = m + log(l). 65536 elems.
// ---------------------------------------------------------------------------
__global__ __launch_bounds__(256) void k_zcomb(const float* __restrict__ mpart,
                                               const float* __restrict__ lpart,
                                               float* __restrict__ zstat) {
    int idx = blockIdx.x * 256 + threadIdx.x;
    float m0 = mpart[idx], m1 = mpart[65536 + idx];
    float l0 = lpart[idx], l1 = lpart[65536 + idx];
    float M = fmaxf(m0, m1);
    float L = l0 * __expf(m0 - M) + l1 * __expf(m1 - M);
    zstat[idx] = M + __logf(L);
}

// ---------------------------------------------------------------------------
// K4 (round-17): r13's verified fused pass (best: 205 us, VGPR 128, no
// spill, 2 blocks/CU) + T5 s_setprio. Occupancy axis is exhausted (r8-r16:
// (2,2)->128 VGPR, (4,4)->64 VGPR + spill, never both regs and waves).
// setprio(1) wraps the MFMA-heavy phases A and C; mix phase B stays prio 0,
// so a block entering MFMA wins issue over the co-resident block's mix VALU
// (phase-role diversity -> T5 applies, +4-7% measured on attn).
// 256-thread / 4-wave blocks, 2 heads per wave (h = wv, wv+4). 66 KB LDS.
// Loop per jt (2 barriers):
//   bar; B(k): S->mix+LN->P; bar; { C(k): P->PV  ||  A(k+1): QK^T+exp->S }
// ---------------------------------------------------------------------------
__global__ __launch_bounds__(256)
__attribute__((amdgpu_waves_per_eu(2, 2)))
void k_fused(const short* __restrict__ Q, const short* __restrict__ Kb,
             const short* __restrict__ Vt, const float* __restrict__ zstat,
             const float* __restrict__ R, const float* __restrict__ rg,
             const float* __restrict__ rb, float* __restrict__ opart) {
    __shared__ short S_lds[8 * 32 * 64];  // [h][32i][64j] bf16, swz — 32 KB
    __shared__ short P_lds[8 * 32 * 64];  // [g][32i][64j] bf16, swz — 32 KB
    __shared__ float Rraw[64], Rc[64], rgs[8], rbs[8], zl[256];
    int b, i0, jh;
    decode_bid2(blockIdx.x, b, i0, jh);
    int tid = threadIdx.x, wv = tid >> 6, lane = tid & 63;
    int fr = lane & 15, fq = lane >> 4;
    if (tid < 64) Rraw[tid] = R[tid];
    if (tid < 8) { rgs[tid] = rg[tid]; rbs[tid] = rb[tid]; }
    zl[tid] = zstat[(size_t)(b * 8 + (tid >> 5)) * Nn + i0 + (tid & 31)];
    __syncthreads();
    if (tid < 64) {
        int h = tid >> 3;
        float mn = 0.f;
#pragma unroll
        for (int gg = 0; gg < 8; ++gg) mn += Rraw[h * 8 + gg];
        Rc[tid] = Rraw[tid] - mn * 0.125f;  // row-centered mix matrix
    }
    // per-wave heads: h0 = wv, h1 = wv + 4
    bf16x8 qf[2][2][2];  // [hp][in][kk]
    float zh[2][2];      // [hp][in]
#pragma unroll
    for (int hp = 0; hp < 2; ++hp) {
        int hh = wv + hp * 4;
        const short* qb = Q + ((size_t)(b * 8 + hh) * Nn + i0) * 64;
#pragma unroll
        for (int in = 0; in < 2; ++in)
#pragma unroll
            for (int kk = 0; kk < 2; ++kk)
                qf[hp][in][kk] = *(const bf16x8*)(qb + (in * 16 + fr) * 64 + kk * 32 + fq * 8);
        zh[hp][0] = zl[hh * 32 + fr];
        zh[hp][1] = zl[hh * 32 + 16 + fr];
    }
    const short* kb0 = Kb + ((size_t)(b * 8 + wv) * Nn + jh * 1024) * 64;
    const short* kb1 = Kb + ((size_t)(b * 8 + wv + 4) * Nn + jh * 1024) * 64;
    const short* vb0 = Vt + (size_t)(b * 8 + wv) * 64 * Nn + jh * 1024;
    const short* vb1 = Vt + (size_t)(b * 8 + wv + 4) * 64 * Nn + jh * 1024;
    const int mi0 = tid >> 4, j4 = (tid & 15) * 4;  // mix ownership
    const int msw = (mi0 & 7) << 4;                 // (mi0+16)&7 == mi0&7
    f32x4 acc_o[2][2][4] = {};  // [hp][im][dn]

    // phase A: QK^T (swapped, prescaled Q) + exp -> S, both heads (setprio 1)
    auto phaseA = [&](int jt) {
        __builtin_amdgcn_s_setprio(1);
#pragma unroll
        for (int hp = 0; hp < 2; ++hp) {
            const short* kb = (hp ? kb1 : kb0) + jt * 64 * 64;
            f32x4 acc[4][2] = {};
#pragma unroll
            for (int kk = 0; kk < 2; ++kk)
#pragma unroll
                for (int jm = 0; jm < 4; ++jm) {
                    bf16x8 kf = *(const bf16x8*)(kb + (jm * 16 + fr) * 64 + kk * 32 + fq * 8);
                    acc[jm][0] = __builtin_amdgcn_mfma_f32_16x16x32_bf16(kf, qf[hp][0][kk], acc[jm][0], 0, 0, 0);
                    acc[jm][1] = __builtin_amdgcn_mfma_f32_16x16x32_bf16(kf, qf[hp][1][kk], acc[jm][1], 0, 0, 0);
                }
            char* Sh = (char*)S_lds + (wv + hp * 4) * 4096;
#pragma unroll
            for (int in = 0; in < 2; ++in) {
                int i = in * 16 + fr;
                int sw = (i & 7) << 4;
#pragma unroll
                for (int jm = 0; jm < 4; ++jm) {
                    bf16x4 pk;
#pragma unroll
                    for (int r = 0; r < 4; ++r)
                        pk[r] = f2bf(__expf(acc[jm][in][r] - zh[hp][in]));
                    int j0 = jm * 16 + fq * 4;
                    *(bf16x4*)(Sh + i * 128 + ((j0 * 2) ^ sw)) = pk;
                }
            }
        }
        __builtin_amdgcn_s_setprio(0);
    };
    // phase B: cross-head mix + head-LN, S -> P (two row-halves per thread)
    auto phaseB = [&]() {
#pragma unroll
        for (int di = 0; di < 32; di += 16) {
            int mi = mi0 + di;
            bf16x4 sh[8];
#pragma unroll
            for (int h = 0; h < 8; ++h)
                sh[h] = *(const bf16x4*)((char*)S_lds + h * 4096 + mi * 128 + ((j4 * 2) ^ msw));
            bf16x4 og[8];
#pragma unroll
            for (int e = 0; e < 4; ++e) {
                float pv[8];
#pragma unroll
                for (int h = 0; h < 8; ++h) pv[h] = bf2f(sh[h][e]);
                float cc[8];
#pragma unroll
                for (int gg = 0; gg < 8; ++gg) {
                    float s = 0.f;
#pragma unroll
                    for (int h = 0; h < 8; ++h) s += pv[h] * Rc[h * 8 + gg];
                    cc[gg] = s;  // mean over gg is 0 by construction
                }
                float var = 0.f;
#pragma unroll
                for (int gg = 0; gg < 8; ++gg) var += cc[gg] * cc[gg];
                var *= 0.125f;
                float rs_ = rsqrtf(var + 1e-5f);
#pragma unroll
                for (int gg = 0; gg < 8; ++gg)
                    og[gg][e] = f2bf(cc[gg] * rs_ * rgs[gg] + rbs[gg]);
            }
#pragma unroll
            for (int gg = 0; gg < 8; ++gg)
                *(bf16x4*)((char*)P_lds + gg * 4096 + mi * 128 + ((j4 * 2) ^ msw)) = og[gg];
        }
    };
    // phase C: PV for both heads, P -> acc_o (setprio 1)
    auto phaseC = [&](int jt) {
        __builtin_amdgcn_s_setprio(1);
#pragma unroll
        for (int hp = 0; hp < 2; ++hp) {
            const short* vb = (hp ? vb1 : vb0) + jt * 64;
            char* Ph = (char*)P_lds + (wv + hp * 4) * 4096;
#pragma unroll
            for (int kk = 0; kk < 2; ++kk) {
                bf16x8 vf[4];
#pragma unroll
                for (int dn = 0; dn < 4; ++dn)
                    vf[dn] = *(const bf16x8*)(vb + (size_t)(dn * 16 + fr) * Nn + kk * 32 + fq * 8);
#pragma unroll
                for (int im = 0; im < 2; ++im) {
                    int row = im * 16 + fr;
                    bf16x8 pa = *(const bf16x8*)(Ph + row * 128 +
                                                 (((kk * 32 + fq * 8) * 2) ^ ((row & 7) << 4)));
#pragma unroll
                    for (int dn = 0; dn < 4; ++dn)
                        acc_o[hp][im][dn] = __builtin_amdgcn_mfma_f32_16x16x32_bf16(pa, vf[dn], acc_o[hp][im][dn], 0, 0, 0);
                }
            }
        }
        __builtin_amdgcn_s_setprio(0);
    };

    phaseA(0);
    for (int k = 0; k < 16; ++k) {
        __syncthreads();   // S(k) ready (first iter: Rc ready too)
        phaseB();
        __syncthreads();   // P(k) ready; B's S-reads done before A rewrites S
        phaseC(k);
        if (k < 15) phaseA(k + 1);
    }

    float* po = opart + (size_t)jh * 4194304 + ((size_t)b * Nn + i0) * 512;
#pragma unroll
    for (int hp = 0; hp < 2; ++hp)
#pragma unroll
        for (int im = 0; im < 2; ++im)
#pragma unroll
            for (int dn = 0; dn < 4; ++dn)
#pragma unroll
                for (int r = 0; r < 4; ++r)
                    po[(im * 16 + fq * 4 + r) * 512 + (wv + hp * 4) * 64 + dn * 16 + fr] =
                        acc_o[hp][im][dn][r];
}

// ---------------------------------------------------------------------------
// K5: sum the two j-half O partials -> outh bf16. 4,194,304 elements.
// ---------------------------------------------------------------------------
__global__ __launch_bounds__(256) void k_osum(const float* __restrict__ opart,
                                              short* __restrict__ outh) {
    int base = (blockIdx.x * 256 + threadIdx.x) * 4;
    f32x4 a = *(const f32x4*)(opart + base);
    f32x4 c = *(const f32x4*)(opart + 4194304 + base);
    bf16x4 o;
#pragma unroll
    for (int t = 0; t < 4; ++t) o[t] = f2bf(a[t] + c[t]);
    *(bf16x4*)(outh + base) = o;
}

extern "C" void kernel_launch(void* const* d_in, const int* in_sizes, int n_in,
                              void* d_out, int out_size, void* d_ws, size_t ws_size,
                              hipStream_t stream) {
    const float* x      = (const float*)d_in[0];
    const float* ln_g   = (const float*)d_in[1];
    const float* ln_b   = (const float*)d_in[2];
    const float* w_qkv  = (const float*)d_in[3];
    const float* reattn = (const float*)d_in[4];
    const float* rn_g   = (const float*)d_in[5];
    const float* rn_b   = (const float*)d_in[6];
    const float* w_out  = (const float*)d_in[7];
    const float* b_out  = (const float*)d_in[8];
    float* out = (float*)d_out;

    char* ws = (char*)d_ws;
    short* wqkvT = (short*)ws; ws += (size_t)1536 * 512 * 2;
    short* woutT = (short*)ws; ws += (size_t)512 * 512 * 2;
    short* xn    = (short*)ws; ws += (size_t)8192 * 512 * 2;   // dead after k_qkv
    short* Q     = (short*)ws; ws += (size_t)32 * 2048 * 64 * 2;
    short* Kb    = (short*)ws; ws += (size_t)32 * 2048 * 64 * 2;
    short* Vt    = (short*)ws; ws += (size_t)32 * 64 * 2048 * 2;
    short* outh  = (short*)ws; ws += (size_t)8192 * 512 * 2;
    float* opart = (float*)ws; ws += (size_t)2 * 4194304 * 4;  // 33.6 MB
    float* mpart = (float*)ws; ws += (size_t)2 * 65536 * 4;
    float* lpart = (float*)ws; ws += (size_t)2 * 65536 * 4;
    // zh stats alias the dead xn region (65536*4 = 256 KB << 8.39 MB)
    float* zstat = (float*)xn;

    k_transpose_cast<<<(512 * 1536 + 255) / 256, 256, 0, stream>>>(w_qkv, wqkvT, 512, 1536);
    k_transpose_cast<<<(512 * 512 + 255) / 256, 256, 0, stream>>>(w_out, woutT, 512, 512);
    k_ln<<<8192 / 4, 256, 0, stream>>>(x, ln_g, ln_b, xn);
    k_qkv<<<dim3(8192 / 128, 1536 / 128), 256, 0, stream>>>(xn, wqkvT, Q, Kb, Vt);

    k_stats<<<512, 512, 0, stream>>>(Q, Kb, mpart, lpart);
    k_zcomb<<<256, 256, 0, stream>>>(mpart, lpart, zstat);
    k_fused<<<512, 256, 0, stream>>>(Q, Kb, Vt, zstat, reattn, rn_g, rn_b, opart);
    k_osum<<<4096, 256, 0, stream>>>(opart, outh);

    k_out<<<dim3(8192 / 128, 512 / 128), 256, 0, stream>>>(outh, woutT, b_out, out);
}

// Round 18
// 306.976 us; speedup vs baseline: 1.7484x; 1.0358x over previous
//
#include <hip/hip_runtime.h>
#include <hip/hip_bf16.h>
#include <math.h>

#define DEV __device__ __forceinline__

typedef short bf16x8 __attribute__((ext_vector_type(8)));
typedef short bf16x4 __attribute__((ext_vector_type(4)));
typedef float f32x4 __attribute__((ext_vector_type(4)));

static const int Nn = 2048;
static const int DIMd = 512;

DEV float bf2f(short u) {
    union { unsigned int i; float f; } c;
    c.i = ((unsigned int)(unsigned short)u) << 16;
    return c.f;
}

DEV short f2bf(float f) {
    union { float f; unsigned int i; } c;
    c.f = f;
    unsigned int u = c.i;
    unsigned int r = (u + 0x7fffu + ((u >> 16) & 1u)) >> 16;
    return (short)r;
}

// async global->LDS, 16B per lane (lane-linear LDS dest required)
DEV void gload16(const short* __restrict__ g, short* l) {
    __builtin_amdgcn_global_load_lds(
        (__attribute__((address_space(1))) void*)g,
        (__attribute__((address_space(3))) void*)l, 16, 0, 0);
}

// ---------------------------------------------------------------------------
// K0: transpose + cast f32 [K][N] -> bf16 [N][K]
// ---------------------------------------------------------------------------
__global__ void k_transpose_cast(const float* __restrict__ src,
                                 short* __restrict__ dst, int K, int N) {
    int o = blockIdx.x * 256 + threadIdx.x;
    if (o >= K * N) return;
    int n = o / K, k = o - n * K;
    dst[o] = f2bf(src[(size_t)k * N + n]);
}

// ---------------------------------------------------------------------------
// K1: row LayerNorm over DIM=512, f32 in -> bf16 out. One wave per row.
// ---------------------------------------------------------------------------
__global__ __launch_bounds__(256) void k_ln(const float* __restrict__ x,
                                            const float* __restrict__ g,
                                            const float* __restrict__ bta,
                                            short* __restrict__ xn) {
    int row = blockIdx.x * 4 + (threadIdx.x >> 6);
    int lane = threadIdx.x & 63;
    const float* xr = x + (size_t)row * DIMd;
    float4 v0 = ((const float4*)xr)[lane * 2];
    float4 v1 = ((const float4*)xr)[lane * 2 + 1];
    float f[8] = {v0.x, v0.y, v0.z, v0.w, v1.x, v1.y, v1.z, v1.w};
    float s = 0.f, sq = 0.f;
#pragma unroll
    for (int t = 0; t < 8; ++t) { s += f[t]; sq += f[t] * f[t]; }
#pragma unroll
    for (int off = 32; off >= 1; off >>= 1) {
        s += __shfl_xor(s, off);
        sq += __shfl_xor(sq, off);
    }
    float mu = s * (1.0f / 512.0f);
    float var = sq * (1.0f / 512.0f) - mu * mu;
    float rs = rsqrtf(var + 1e-5f);
    bf16x8 o;
#pragma unroll
    for (int t = 0; t < 8; ++t) {
        int c = lane * 8 + t;
        o[t] = f2bf((f[t] - mu) * rs * g[c] + bta[c]);
    }
    *(bf16x8*)(xn + (size_t)row * DIMd + lane * 8) = o;
}

// ---------------------------------------------------------------------------
// m97-style 128x128 tile GEMM main loop (A [M][K], B^T [N][K], k-contig).
// ---------------------------------------------------------------------------
DEV void gemm128_loop(const short* __restrict__ A, const short* __restrict__ B,
                      int K, int i0, int n0, int tid,
                      short* As, short* Bs, f32x4 acc[4][4]) {
    const int w = tid >> 6, wr = w >> 1, wc = w & 1;
    const int lane = tid & 63, fr = lane & 15, fq = lane >> 4;
    const int sr = tid >> 3, sc = (tid & 7) * 8;
    for (int k0 = 0; k0 < K; k0 += 64) {
#pragma unroll
        for (int L = 0; L < 4; ++L) {
            gload16(A + (size_t)(i0 + L * 32 + sr) * K + k0 + sc,
                    As + (L * 32 + sr) * 64 + sc);
            gload16(B + (size_t)(n0 + L * 32 + sr) * K + k0 + sc,
                    Bs + (L * 32 + sr) * 64 + sc);
        }
        __syncthreads();
#pragma unroll
        for (int kk = 0; kk < 2; ++kk) {
            bf16x8 af[4], bfr[4];
#pragma unroll
            for (int m = 0; m < 4; ++m)
                af[m] = *(const bf16x8*)(As + (wr * 64 + m * 16 + fr) * 64 + kk * 32 + fq * 8);
#pragma unroll
            for (int n = 0; n < 4; ++n)
                bfr[n] = *(const bf16x8*)(Bs + (wc * 64 + n * 16 + fr) * 64 + kk * 32 + fq * 8);
#pragma unroll
            for (int m = 0; m < 4; ++m)
#pragma unroll
                for (int n = 0; n < 4; ++n)
                    acc[m][n] = __builtin_amdgcn_mfma_f32_16x16x32_bf16(af[m], bfr[n], acc[m][n], 0, 0, 0);
        }
        __syncthreads();
    }
}

// ---------------------------------------------------------------------------
// K2: qkv = xn @ w_qkvT^T. Scatter epilogue into Q, K (k-contig) and Vt.
// Q is PRESCALED by 0.125 (exact pow-2) so scores come out of MFMA scaled.
// ---------------------------------------------------------------------------
__global__ __launch_bounds__(256) void k_qkv(const short* __restrict__ xn,
                                             const short* __restrict__ wT,
                                             short* __restrict__ Q,
                                             short* __restrict__ Kb,
                                             short* __restrict__ Vt) {
    __shared__ short As[128 * 64], Bs[128 * 64];
    int tid = threadIdx.x;
    int i0 = blockIdx.x * 128, n0 = blockIdx.y * 128;
    f32x4 acc[4][4] = {};
    gemm128_loop(xn, wT, DIMd, i0, n0, tid, As, Bs, acc);
    const int w = tid >> 6, wr = w >> 1, wc = w & 1;
    const int lane = tid & 63, fr = lane & 15, fq = lane >> 4;
#pragma unroll
    for (int m = 0; m < 4; ++m) {
#pragma unroll
        for (int n = 0; n < 4; ++n) {
#pragma unroll
            for (int r = 0; r < 4; ++r) {
                int row = i0 + wr * 64 + m * 16 + fq * 4 + r;
                int c = n0 + wc * 64 + n * 16 + fr;
                float v = acc[m][n][r];
                int b = row >> 11, i = row & 2047;
                int t = c >> 9, rem = c & 511;
                int h = rem >> 6, dd = rem & 63;
                size_t bh = (size_t)(b * 8 + h);
                if (t == 0)      Q [(bh * Nn + i) * 64 + dd] = f2bf(v * 0.125f);
                else if (t == 1) Kb[(bh * Nn + i) * 64 + dd] = f2bf(v);
                else             Vt[(bh * 64 + dd) * Nn + i] = f2bf(v);
            }
        }
    }
}

// ---------------------------------------------------------------------------
// K6: final = out_h @ w_outT^T + b_out. f32 out.
// ---------------------------------------------------------------------------
__global__ __launch_bounds__(256) void k_out(const short* __restrict__ outh,
                                             const short* __restrict__ wT,
                                             const float* __restrict__ bias,
                                             float* __restrict__ out) {
    __shared__ short As[128 * 64], Bs[128 * 64];
    int tid = threadIdx.x;
    int i0 = blockIdx.x * 128, n0 = blockIdx.y * 128;
    f32x4 acc[4][4] = {};
    gemm128_loop(outh, wT, 512, i0, n0, tid, As, Bs, acc);
    const int w = tid >> 6, wr = w >> 1, wc = w & 1;
    const int lane = tid & 63, fr = lane & 15, fq = lane >> 4;
#pragma unroll
    for (int m = 0; m < 4; ++m)
#pragma unroll
        for (int n = 0; n < 4; ++n)
#pragma unroll
            for (int r = 0; r < 4; ++r) {
                int row = i0 + wr * 64 + m * 16 + fq * 4 + r;
                int c = n0 + wc * 64 + n * 16 + fr;
                out[(size_t)row * 512 + c] = acc[m][n][r] + bias[c];
            }
}

// XCD-aware decode of a 512-block 1-D grid into (b, i0, jh). Blocks sharing
// (b, jh) land on one XCD => that XCD's L2 holds one K/V half-panel.
DEV void decode_bid2(int bid, int& b, int& i0, int& jh) {
    int xcd = bid & 7, slot = bid >> 3;  // slot 0..63
    b = xcd >> 1;
    jh = xcd & 1;
    i0 = slot * 32;
}

// ---------------------------------------------------------------------------
// K3a: stats partials. Block = (b, i0, jh); wave h owns head h, 32 q-rows,
// 1024 j (16 jt). Swapped QK^T on prescaled Q. Partial (m, l) per (bh, i).
// ---------------------------------------------------------------------------
__global__ __launch_bounds__(512)
__attribute__((amdgpu_waves_per_eu(4, 4)))
void k_stats(const short* __restrict__ Q,
             const short* __restrict__ Kb,
             float* __restrict__ mpart,
             float* __restrict__ lpart) {
    int b, i0, jh;
    decode_bid2(blockIdx.x, b, i0, jh);
    int tid = threadIdx.x, wv = tid >> 6, lane = tid & 63;
    int fr = lane & 15, fq = lane >> 4;
    size_t bh = (size_t)(b * 8 + wv);
    const short* qb = Q + (bh * Nn + i0) * 64;
    bf16x8 qf[2][2];
#pragma unroll
    for (int in = 0; in < 2; ++in)
#pragma unroll
        for (int kk = 0; kk < 2; ++kk)
            qf[in][kk] = *(const bf16x8*)(qb + (in * 16 + fr) * 64 + kk * 32 + fq * 8);
    float m[2] = {-1e30f, -1e30f}, l[2] = {0.f, 0.f};
    const short* kbase = Kb + bh * Nn * 64 + (size_t)jh * 1024 * 64;
    for (int jt = 0; jt < 16; ++jt) {
        const short* kb = kbase + jt * 64 * 64;
        f32x4 acc[4][2] = {};
#pragma unroll
        for (int kk = 0; kk < 2; ++kk)
#pragma unroll
            for (int jm = 0; jm < 4; ++jm) {
                bf16x8 kf = *(const bf16x8*)(kb + (jm * 16 + fr) * 64 + kk * 32 + fq * 8);
                acc[jm][0] = __builtin_amdgcn_mfma_f32_16x16x32_bf16(kf, qf[0][kk], acc[jm][0], 0, 0, 0);
                acc[jm][1] = __builtin_amdgcn_mfma_f32_16x16x32_bf16(kf, qf[1][kk], acc[jm][1], 0, 0, 0);
            }
#pragma unroll
        for (int in = 0; in < 2; ++in) {
            float mt = acc[0][in][0];
#pragma unroll
            for (int jm = 0; jm < 4; ++jm)
#pragma unroll
                for (int r = 0; r < 4; ++r) mt = fmaxf(mt, acc[jm][in][r]);
            mt = fmaxf(mt, __shfl_xor(mt, 16));
            mt = fmaxf(mt, __shfl_xor(mt, 32));
            float es = 0.f;
#pragma unroll
            for (int jm = 0; jm < 4; ++jm)
#pragma unroll
                for (int r = 0; r < 4; ++r)
                    es += __expf(acc[jm][in][r] - mt);
            es += __shfl_xor(es, 16);
            es += __shfl_xor(es, 32);
            float mn = fmaxf(m[in], mt);
            l[in] = l[in] * __expf(m[in] - mn) + es * __expf(mt - mn);
            m[in] = mn;
        }
    }
    if (fq == 0) {
#pragma unroll
        for (int in = 0; in < 2; ++in) {
            size_t o = (size_t)jh * 65536 + bh * Nn + i0 + in * 16 + fr;
            mpart[o] = m[in];
            lpart[o] = l[in];
        }
    }
}

// ---------------------------------------------------------------------------
// K3b: combine the two j-half stats -> zh = m + log(l). 65536 elems.
// ---------------------------------------------------------------------------
__global__ __launch_bounds__(256) void k_zcomb(const float* __restrict__ mpart,
                                               const float* __restrict__ lpart,
                                               float* __restrict__ zstat) {
    int idx = blockIdx.x * 256 + threadIdx.x;
    float m0 = mpart[idx], m1 = mpart[65536 + idx];
    float l0 = lpart[idx], l1 = lpart[65536 + idx];
    float M = fmaxf(m0, m1);
    float L = l0 * __expf(m0 - M) + l1 * __expf(m1 - M);
    zstat[idx] = M + __logf(L);
}

// ---------------------------------------------------------------------------
// K4 (final = round-13 verified optimum): fused pass, 256-thread / 4-wave
// blocks, 2 heads per wave (h = wv, wv+4). Single-buffered S/P LDS (66 KB)
// => two co-resident blocks per CU at waves_per_eu(2,2) (128-VGPR cap, no
// spill — measured VGPR 128, WRITE 49 MB). Loop per jt (2 barriers):
//   bar; B(k): S->mix+LN->P; bar; { C(k): P->PV  ||  A(k+1): QK^T+exp->S }
// Hazards: B(k) reads S pre-bar2, A(k+1) rewrites S post-bar2; C(k) reads P
// pre-bar1(k+1), B(k+1) rewrites P post-bar1(k+1). All crossings barriered.
// Exploration summary (r8-r17): occupancy knobs ((4,4)->64 VGPR + spill),
// tile halving, 1-barrier dbuf pipeline, barrier-free in-register variant
// (needs 256 VGPR for partials), and setprio all plateaued or regressed;
// this configuration is the empirical optimum of the structure.
// ---------------------------------------------------------------------------
__global__ __launch_bounds__(256)
__attribute__((amdgpu_waves_per_eu(2, 2)))
void k_fused(const short* __restrict__ Q, const short* __restrict__ Kb,
             const short* __restrict__ Vt, const float* __restrict__ zstat,
             const float* __restrict__ R, const float* __restrict__ rg,
             const float* __restrict__ rb, float* __restrict__ opart) {
    __shared__ short S_lds[8 * 32 * 64];  // [h][32i][64j] bf16, swz — 32 KB
    __shared__ short P_lds[8 * 32 * 64];  // [g][32i][64j] bf16, swz — 32 KB
    __shared__ float Rraw[64], Rc[64], rgs[8], rbs[8], zl[256];
    int b, i0, jh;
    decode_bid2(blockIdx.x, b, i0, jh);
    int tid = threadIdx.x, wv = tid >> 6, lane = tid & 63;
    int fr = lane & 15, fq = lane >> 4;
    if (tid < 64) Rraw[tid] = R[tid];
    if (tid < 8) { rgs[tid] = rg[tid]; rbs[tid] = rb[tid]; }
    zl[tid] = zstat[(size_t)(b * 8 + (tid >> 5)) * Nn + i0 + (tid & 31)];
    __syncthreads();
    if (tid < 64) {
        int h = tid >> 3;
        float mn = 0.f;
#pragma unroll
        for (int gg = 0; gg < 8; ++gg) mn += Rraw[h * 8 + gg];
        Rc[tid] = Rraw[tid] - mn * 0.125f;  // row-centered mix matrix
    }
    // per-wave heads: h0 = wv, h1 = wv + 4
    bf16x8 qf[2][2][2];  // [hp][in][kk]
    float zh[2][2];      // [hp][in]
#pragma unroll
    for (int hp = 0; hp < 2; ++hp) {
        int hh = wv + hp * 4;
        const short* qb = Q + ((size_t)(b * 8 + hh) * Nn + i0) * 64;
#pragma unroll
        for (int in = 0; in < 2; ++in)
#pragma unroll
            for (int kk = 0; kk < 2; ++kk)
                qf[hp][in][kk] = *(const bf16x8*)(qb + (in * 16 + fr) * 64 + kk * 32 + fq * 8);
        zh[hp][0] = zl[hh * 32 + fr];
        zh[hp][1] = zl[hh * 32 + 16 + fr];
    }
    const short* kb0 = Kb + ((size_t)(b * 8 + wv) * Nn + jh * 1024) * 64;
    const short* kb1 = Kb + ((size_t)(b * 8 + wv + 4) * Nn + jh * 1024) * 64;
    const short* vb0 = Vt + (size_t)(b * 8 + wv) * 64 * Nn + jh * 1024;
    const short* vb1 = Vt + (size_t)(b * 8 + wv + 4) * 64 * Nn + jh * 1024;
    const int mi0 = tid >> 4, j4 = (tid & 15) * 4;  // mix ownership
    const int msw = (mi0 & 7) << 4;                 // (mi0+16)&7 == mi0&7
    f32x4 acc_o[2][2][4] = {};  // [hp][im][dn]

    // phase A: QK^T (swapped, prescaled Q) + exp -> S, both heads
    auto phaseA = [&](int jt) {
#pragma unroll
        for (int hp = 0; hp < 2; ++hp) {
            const short* kb = (hp ? kb1 : kb0) + jt * 64 * 64;
            f32x4 acc[4][2] = {};
#pragma unroll
            for (int kk = 0; kk < 2; ++kk)
#pragma unroll
                for (int jm = 0; jm < 4; ++jm) {
                    bf16x8 kf = *(const bf16x8*)(kb + (jm * 16 + fr) * 64 + kk * 32 + fq * 8);
                    acc[jm][0] = __builtin_amdgcn_mfma_f32_16x16x32_bf16(kf, qf[hp][0][kk], acc[jm][0], 0, 0, 0);
                    acc[jm][1] = __builtin_amdgcn_mfma_f32_16x16x32_bf16(kf, qf[hp][1][kk], acc[jm][1], 0, 0, 0);
                }
            char* Sh = (char*)S_lds + (wv + hp * 4) * 4096;
#pragma unroll
            for (int in = 0; in < 2; ++in) {
                int i = in * 16 + fr;
                int sw = (i & 7) << 4;
#pragma unroll
                for (int jm = 0; jm < 4; ++jm) {
                    bf16x4 pk;
#pragma unroll
                    for (int r = 0; r < 4; ++r)
                        pk[r] = f2bf(__expf(acc[jm][in][r] - zh[hp][in]));
                    int j0 = jm * 16 + fq * 4;
                    *(bf16x4*)(Sh + i * 128 + ((j0 * 2) ^ sw)) = pk;
                }
            }
        }
    };
    // phase B: cross-head mix + head-LN, S -> P (two row-halves per thread)
    auto phaseB = [&]() {
#pragma unroll
        for (int di = 0; di < 32; di += 16) {
            int mi = mi0 + di;
            bf16x4 sh[8];
#pragma unroll
            for (int h = 0; h < 8; ++h)
                sh[h] = *(const bf16x4*)((char*)S_lds + h * 4096 + mi * 128 + ((j4 * 2) ^ msw));
            bf16x4 og[8];
#pragma unroll
            for (int e = 0; e < 4; ++e) {
                float pv[8];
#pragma unroll
                for (int h = 0; h < 8; ++h) pv[h] = bf2f(sh[h][e]);
                float cc[8];
#pragma unroll
                for (int gg = 0; gg < 8; ++gg) {
                    float s = 0.f;
#pragma unroll
                    for (int h = 0; h < 8; ++h) s += pv[h] * Rc[h * 8 + gg];
                    cc[gg] = s;  // mean over gg is 0 by construction
                }
                float var = 0.f;
#pragma unroll
                for (int gg = 0; gg < 8; ++gg) var += cc[gg] * cc[gg];
                var *= 0.125f;
                float rs_ = rsqrtf(var + 1e-5f);
#pragma unroll
                for (int gg = 0; gg < 8; ++gg)
                    og[gg][e] = f2bf(cc[gg] * rs_ * rgs[gg] + rbs[gg]);
            }
#pragma unroll
            for (int gg = 0; gg < 8; ++gg)
                *(bf16x4*)((char*)P_lds + gg * 4096 + mi * 128 + ((j4 * 2) ^ msw)) = og[gg];
        }
    };
    // phase C: PV for both heads, P -> acc_o
    auto phaseC = [&](int jt) {
#pragma unroll
        for (int hp = 0; hp < 2; ++hp) {
            const short* vb = (hp ? vb1 : vb0) + jt * 64;
            char* Ph = (char*)P_lds + (wv + hp * 4) * 4096;
#pragma unroll
            for (int kk = 0; kk < 2; ++kk) {
                bf16x8 vf[4];
#pragma unroll
                for (int dn = 0; dn < 4; ++dn)
                    vf[dn] = *(const bf16x8*)(vb + (size_t)(dn * 16 + fr) * Nn + kk * 32 + fq * 8);
#pragma unroll
                for (int im = 0; im < 2; ++im) {
                    int row = im * 16 + fr;
                    bf16x8 pa = *(const bf16x8*)(Ph + row * 128 +
                                                 (((kk * 32 + fq * 8) * 2) ^ ((row & 7) << 4)));
#pragma unroll
                    for (int dn = 0; dn < 4; ++dn)
                        acc_o[hp][im][dn] = __builtin_amdgcn_mfma_f32_16x16x32_bf16(pa, vf[dn], acc_o[hp][im][dn], 0, 0, 0);
                }
            }
        }
    };

    phaseA(0);
    for (int k = 0; k < 16; ++k) {
        __syncthreads();   // S(k) ready (first iter: Rc ready too)
        phaseB();
        __syncthreads();   // P(k) ready; B's S-reads done before A rewrites S
        phaseC(k);
        if (k < 15) phaseA(k + 1);
    }

    float* po = opart + (size_t)jh * 4194304 + ((size_t)b * Nn + i0) * 512;
#pragma unroll
    for (int hp = 0; hp < 2; ++hp)
#pragma unroll
        for (int im = 0; im < 2; ++im)
#pragma unroll
            for (int dn = 0; dn < 4; ++dn)
#pragma unroll
                for (int r = 0; r < 4; ++r)
                    po[(im * 16 + fq * 4 + r) * 512 + (wv + hp * 4) * 64 + dn * 16 + fr] =
                        acc_o[hp][im][dn][r];
}

// ---------------------------------------------------------------------------
// K5: sum the two j-half O partials -> outh bf16. 4,194,304 elements.
// ---------------------------------------------------------------------------
__global__ __launch_bounds__(256) void k_osum(const float* __restrict__ opart,
                                              short* __restrict__ outh) {
    int base = (blockIdx.x * 256 + threadIdx.x) * 4;
    f32x4 a = *(const f32x4*)(opart + base);
    f32x4 c = *(const f32x4*)(opart + 4194304 + base);
    bf16x4 o;
#pragma unroll
    for (int t = 0; t < 4; ++t) o[t] = f2bf(a[t] + c[t]);
    *(bf16x4*)(outh + base) = o;
}

extern "C" void kernel_launch(void* const* d_in, const int* in_sizes, int n_in,
                              void* d_out, int out_size, void* d_ws, size_t ws_size,
                              hipStream_t stream) {
    const float* x      = (const float*)d_in[0];
    const float* ln_g   = (const float*)d_in[1];
    const float* ln_b   = (const float*)d_in[2];
    const float* w_qkv  = (const float*)d_in[3];
    const float* reattn = (const float*)d_in[4];
    const float* rn_g   = (const float*)d_in[5];
    const float* rn_b   = (const float*)d_in[6];
    const float* w_out  = (const float*)d_in[7];
    const float* b_out  = (const float*)d_in[8];
    float* out = (float*)d_out;

    char* ws = (char*)d_ws;
    short* wqkvT = (short*)ws; ws += (size_t)1536 * 512 * 2;
    short* woutT = (short*)ws; ws += (size_t)512 * 512 * 2;
    short* xn    = (short*)ws; ws += (size_t)8192 * 512 * 2;   // dead after k_qkv
    short* Q     = (short*)ws; ws += (size_t)32 * 2048 * 64 * 2;
    short* Kb    = (short*)ws; ws += (size_t)32 * 2048 * 64 * 2;
    short* Vt    = (short*)ws; ws += (size_t)32 * 64 * 2048 * 2;
    short* outh  = (short*)ws; ws += (size_t)8192 * 512 * 2;
    float* opart = (float*)ws; ws += (size_t)2 * 4194304 * 4;  // 33.6 MB
    float* mpart = (float*)ws; ws += (size_t)2 * 65536 * 4;
    float* lpart = (float*)ws; ws += (size_t)2 * 65536 * 4;
    // zh stats alias the dead xn region (65536*4 = 256 KB << 8.39 MB)
    float* zstat = (float*)xn;

    k_transpose_cast<<<(512 * 1536 + 255) / 256, 256, 0, stream>>>(w_qkv, wqkvT, 512, 1536);
    k_transpose_cast<<<(512 * 512 + 255) / 256, 256, 0, stream>>>(w_out, woutT, 512, 512);
    k_ln<<<8192 / 4, 256, 0, stream>>>(x, ln_g, ln_b, xn);
    k_qkv<<<dim3(8192 / 128, 1536 / 128), 256, 0, stream>>>(xn, wqkvT, Q, Kb, Vt);

    k_stats<<<512, 512, 0, stream>>>(Q, Kb, mpart, lpart);
    k_zcomb<<<256, 256, 0, stream>>>(mpart, lpart, zstat);
    k_fused<<<512, 256, 0, stream>>>(Q, Kb, Vt, zstat, reattn, rn_g, rn_b, opart);
    k_osum<<<4096, 256, 0, stream>>>(opart, outh);

    k_out<<<dim3(8192 / 128, 512 / 128), 256, 0, stream>>>(outh, woutT, b_out, out);
}